// Round 5
// baseline (153.283 us; speedup 1.0000x reference)
//
#include <hip/hip_runtime.h>
#include <math.h>

// Problem constants (fixed by the reference)
#define NE   4
#define NH   64
#define NG   64            // N
#define NB   8
#define NL   8
#define ND   128
#define NDIA 110
#define NK   (NDIA*NB*NG)  // 56320
#define NBN  (NB*NG)       // 512
#define NVOX (NH*NG*NG)    // 262144

typedef int   v2i __attribute__((ext_vector_type(2)));
typedef float v2f __attribute__((ext_vector_type(2)));

// Kernel 1: rotate grid_concentration (bilinear, zero-pad) + xp overwrite,
// store voxel-major OCP fp8(e4m3)x4: conc_t[v] = pack{conc[e=0..3, v]}.
// 4 B/voxel -> 1 MB table, fully L2-resident (verified: FETCH dropped to the
// stream-only level in R4).
__global__ __launch_bounds__(256) void k_rotate(
    const float* __restrict__ grid, const float* __restrict__ xp,
    const float* __restrict__ theta_ls, const int* __restrict__ tidx,
    const int* __restrict__ pscal, unsigned int* __restrict__ conc_t)
{
  int v = blockIdx.x * 256 + threadIdx.x;          // voxel id, 0..NVOX-1
  int h = v >> 12;
  int i = (v >> 6) & 63;                            // row
  int j = v & 63;                                   // col
  float theta = theta_ls[tidx[0]];
  float st, ct;
  sincosf(theta, &st, &ct);
  const float c = 31.5f;                            // (N-1)/2
  float x = (float)j - c, y = (float)i - c;
  float xs = ct * x - st * y + c;
  float ys = st * x + ct * y + c;
  float x0f = floorf(xs), y0f = floorf(ys);
  int x0 = (int)x0f, y0 = (int)y0f;
  float wx = xs - x0f, wy = ys - y0f;
  int x1 = x0 + 1, y1 = y0 + 1;
  bool vx0 = (unsigned)x0 < 64u, vx1 = (unsigned)x1 < 64u;
  bool vy0 = (unsigned)y0 < 64u, vy1 = (unsigned)y1 < 64u;
  float w00 = (vy0 && vx0) ? (1.f - wy) * (1.f - wx) : 0.f;
  float w01 = (vy0 && vx1) ? (1.f - wy) * wx         : 0.f;
  float w10 = (vy1 && vx0) ? wy * (1.f - wx)         : 0.f;
  float w11 = (vy1 && vx1) ? wy * wx                 : 0.f;
  int xc0 = min(max(x0, 0), 63), xc1 = min(max(x1, 0), 63);
  int yc0 = min(max(y0, 0), 63), yc1 = min(max(y1, 0), 63);
  int i00 = yc0 * 64 + xc0, i01 = yc0 * 64 + xc1;
  int i10 = yc1 * 64 + xc0, i11 = yc1 * 64 + xc1;
  int hn = (h << 6) | i;                            // flattened H*N row
  int pb = 8 * pscal[0];                            // B*p
  bool ov = (hn >= pb) && (hn < pb + 8);
  int xoff = ov ? (((hn - pb) << 6) | j) : 0;
  float o[4];
#pragma unroll
  for (int e = 0; e < NE; e++) {
    const float* g = grid + (((e << 6) + h) << 12); // (e*H + h)*N*N
    float val = w00 * g[i00] + w01 * g[i01] + w10 * g[i10] + w11 * g[i11];
    if (ov) val = xp[(e << 9) + xoff];              // xp[e, hn-pb, j]
    o[e] = val;
  }
  unsigned int packed = 0;
  packed = __builtin_amdgcn_cvt_pk_fp8_f32(o[0], o[1], packed, false); // low word
  packed = __builtin_amdgcn_cvt_pk_fp8_f32(o[2], o[3], packed, true);  // high word
  conc_t[v] = packed;
}

// Kernel 2: per (d, v) ray sums over 110 path entries. 4 lanes cooperate
// (28/28/28/26 split, 14 fully-unrolled int2 iterations -> up to 28
// independent gathers in flight per lane for latency hiding). After the
// 2-round shuffle combine, each lane emits lines l=q and l=q+4:
// expval[d][l][v] = exp(-sum_e FL[e,l]*per_ray[e]).
__global__ __launch_bounds__(256) void k_rays(
    const int* __restrict__ P_idx, const float* __restrict__ P_len,
    const unsigned int* __restrict__ conc_t, const float* __restrict__ FLp,
    float* __restrict__ expval)
{
  int q = threadIdx.x & 3;                          // quarter of the ray
  int ray = (blockIdx.x << 6) | (threadIdx.x >> 2); // (d,v) id, 0..65535
  int d = ray >> 9;
  int v = ray & 511;
  size_t off = (size_t)d * NK + (size_t)v * NDIA + (size_t)(q * 28);
  const v2i* ip = (const v2i*)(P_idx + off);
  const v2f* lp = (const v2f*)(P_len + off);
  int cnt = (q == 3) ? 13 : 14;                     // int2 pairs (tail lane: 26 entries)
  float a0 = 0.f, a1 = 0.f, a2 = 0.f, a3 = 0.f;
#pragma unroll
  for (int t = 0; t < 14; t++) {
    if (t < cnt) {
      v2i id = ip[t];
      v2f ln = lp[t];
      unsigned int u0 = conc_t[id.x];
      unsigned int u1 = conc_t[id.y];
      v2f c01 = __builtin_amdgcn_cvt_pk_f32_fp8(u0, false);
      v2f c23 = __builtin_amdgcn_cvt_pk_f32_fp8(u0, true);
      v2f d01 = __builtin_amdgcn_cvt_pk_f32_fp8(u1, false);
      v2f d23 = __builtin_amdgcn_cvt_pk_f32_fp8(u1, true);
      a0 += c01.x * ln.x + d01.x * ln.y;
      a1 += c01.y * ln.x + d01.y * ln.y;
      a2 += c23.x * ln.x + d23.x * ln.y;
      a3 += c23.y * ln.x + d23.y * ln.y;
    }
  }
  // combine the 4 cooperating lanes (adjacent in the wave)
  a0 += __shfl_xor(a0, 1); a1 += __shfl_xor(a1, 1);
  a2 += __shfl_xor(a2, 1); a3 += __shfl_xor(a3, 1);
  a0 += __shfl_xor(a0, 2); a1 += __shfl_xor(a1, 2);
  a2 += __shfl_xor(a2, 2); a3 += __shfl_xor(a3, 2);
  // lines l = q and l = q+4
  float s0 = FLp[q]      * a0 + FLp[8 + q]  * a1 + FLp[16 + q] * a2 + FLp[24 + q] * a3;
  float s1 = FLp[4 + q]  * a0 + FLp[12 + q] * a1 + FLp[20 + q] * a2 + FLp[28 + q] * a3;
  size_t base = ((size_t)d << 12) + v;              // d*L*BN + l*BN + v
  expval[base + ((size_t)q << 9)]       = __expf(-s0);
  expval[base + ((size_t)(q + 4) << 9)] = __expf(-s1);
}

// Kernel 3: SA = mean_d expval; apply probe attenuation (shfl prefix scan) and
// fl_map, reduce over n. Block = (l,b); 256 threads = 4 d-chunks x 64 n.
__global__ __launch_bounds__(256) void k_final(
    const float* __restrict__ expval, const float* __restrict__ xp,
    const float* __restrict__ attCS, const float* __restrict__ dfl,
    const float* __restrict__ scm, const float* __restrict__ pcts,
    const int* __restrict__ l2e, float* __restrict__ out)
{
  __shared__ float red[256];
  int l = blockIdx.x >> 3;
  int b = blockIdx.x & 7;
  int n = threadIdx.x & 63;
  int dc = threadIdx.x >> 6;                        // d-chunk 0..3
  int v = (b << 6) | n;
  const float* ep = expval + (l << 9) + v;
  float s = 0.f;
#pragma unroll
  for (int t = 0; t < 32; t++) s += ep[(size_t)(dc * 32 + t) << 12];
  red[threadIdx.x] = s;
  __syncthreads();
  if (dc == 0) {
    float sa = red[n] + red[n + 64] + red[n + 128] + red[n + 192];
    float dx = scm[0] * (1.0f / 64.0f);
    float pc = pcts[0];
    float lac = attCS[0] * xp[v] + attCS[1] * xp[512 + v]
              + attCS[2] * xp[1024 + v] + attCS[3] * xp[1536 + v];
    // inclusive prefix scan of lac over the 64 lanes (n)
    float inc = lac;
#pragma unroll
    for (int ofs = 1; ofs < 64; ofs <<= 1) {
      float t = __shfl_up(inc, ofs, 64);
      if (n >= ofs) inc += t;
    }
    float pre = inc - lac;                          // exclusive prefix
    float att = __expf(-dx * pre);
    float val = pc * att * xp[(l2e[l] << 9) + v] * dfl[l] * sa * (1.0f / 128.0f);
#pragma unroll
    for (int ofs = 32; ofs > 0; ofs >>= 1) val += __shfl_down(val, ofs, 64);
    if (n == 0) out[(l << 3) + b] = val;
    if (l == 0 && n == 63) out[64 + b] = pc * __expf(-dx * inc);
  }
}

extern "C" void kernel_launch(void* const* d_in, const int* in_sizes, int n_in,
                              void* d_out, int out_size, void* d_ws, size_t ws_size,
                              hipStream_t stream) {
  const float* grid_c   = (const float*)d_in[0];   // (E,H,N,N)
  const float* xp       = (const float*)d_in[1];   // (E,B,N)
  const float* theta_ls = (const float*)d_in[2];   // (16,)
  const float* attCS    = (const float*)d_in[3];   // (E,)
  const float* FLp      = (const float*)d_in[4];   // (E,L)
  const float* dfl      = (const float*)d_in[5];   // (L,)
  const float* P_len    = (const float*)d_in[6];   // (D,K)
  const float* scm      = (const float*)d_in[7];   // scalar
  const float* pcts     = (const float*)d_in[8];   // scalar
  const int*   l2e      = (const int*)d_in[9];     // (L,)
  const int*   P_idx    = (const int*)d_in[10];    // (D,K)
  const int*   tidx     = (const int*)d_in[11];    // scalar
  const int*   pscal    = (const int*)d_in[12];    // scalar
  float* out = (float*)d_out;                      // 64 (out1) + 8 (out2)

  unsigned int* conc_t = (unsigned int*)d_ws;      // NVOX * 4 B = 1 MB
  float* expval = (float*)((char*)d_ws + (size_t)NVOX * 4); // D*L*BN floats = 2 MB

  k_rotate<<<NVOX / 256, 256, 0, stream>>>(grid_c, xp, theta_ls, tidx, pscal, conc_t);
  k_rays<<<(ND * NBN) / 64, 256, 0, stream>>>(P_idx, P_len, conc_t, FLp, expval);
  k_final<<<NL * NB, 256, 0, stream>>>(expval, xp, attCS, dfl, scm, pcts, l2e, out);
}

// Round 6
// 150.094 us; speedup vs baseline: 1.0212x; 1.0212x over previous
//
#include <hip/hip_runtime.h>
#include <math.h>

// Problem constants (fixed by the reference)
#define NE   4
#define NH   64
#define NG   64            // N
#define NB   8
#define NL   8
#define ND   128
#define NDIA 110
#define NK   (NDIA*NB*NG)  // 56320
#define NBN  (NB*NG)       // 512
#define NVOX (NH*NG*NG)    // 262144

typedef float v2f __attribute__((ext_vector_type(2)));

// Kernel 1: rotate grid_concentration (bilinear, zero-pad) + xp overwrite,
// store voxel-major OCP fp8(e4m3)x4: conc_t[v] = pack{conc[e=0..3, v]}.
// 4 B/voxel -> 1 MB table, fully L2-resident (verified R4: FETCH at
// stream-only level).
__global__ __launch_bounds__(256) void k_rotate(
    const float* __restrict__ grid, const float* __restrict__ xp,
    const float* __restrict__ theta_ls, const int* __restrict__ tidx,
    const int* __restrict__ pscal, unsigned int* __restrict__ conc_t)
{
  int v = blockIdx.x * 256 + threadIdx.x;          // voxel id, 0..NVOX-1
  int h = v >> 12;
  int i = (v >> 6) & 63;                            // row
  int j = v & 63;                                   // col
  float theta = theta_ls[tidx[0]];
  float st, ct;
  sincosf(theta, &st, &ct);
  const float c = 31.5f;                            // (N-1)/2
  float x = (float)j - c, y = (float)i - c;
  float xs = ct * x - st * y + c;
  float ys = st * x + ct * y + c;
  float x0f = floorf(xs), y0f = floorf(ys);
  int x0 = (int)x0f, y0 = (int)y0f;
  float wx = xs - x0f, wy = ys - y0f;
  int x1 = x0 + 1, y1 = y0 + 1;
  bool vx0 = (unsigned)x0 < 64u, vx1 = (unsigned)x1 < 64u;
  bool vy0 = (unsigned)y0 < 64u, vy1 = (unsigned)y1 < 64u;
  float w00 = (vy0 && vx0) ? (1.f - wy) * (1.f - wx) : 0.f;
  float w01 = (vy0 && vx1) ? (1.f - wy) * wx         : 0.f;
  float w10 = (vy1 && vx0) ? wy * (1.f - wx)         : 0.f;
  float w11 = (vy1 && vx1) ? wy * wx                 : 0.f;
  int xc0 = min(max(x0, 0), 63), xc1 = min(max(x1, 0), 63);
  int yc0 = min(max(y0, 0), 63), yc1 = min(max(y1, 0), 63);
  int i00 = yc0 * 64 + xc0, i01 = yc0 * 64 + xc1;
  int i10 = yc1 * 64 + xc0, i11 = yc1 * 64 + xc1;
  int hn = (h << 6) | i;                            // flattened H*N row
  int pb = 8 * pscal[0];                            // B*p
  bool ov = (hn >= pb) && (hn < pb + 8);
  int xoff = ov ? (((hn - pb) << 6) | j) : 0;
  float o[4];
#pragma unroll
  for (int e = 0; e < NE; e++) {
    const float* g = grid + (((e << 6) + h) << 12); // (e*H + h)*N*N
    float val = w00 * g[i00] + w01 * g[i01] + w10 * g[i10] + w11 * g[i11];
    if (ov) val = xp[(e << 9) + xoff];              // xp[e, hn-pb, j]
    o[e] = val;
  }
  unsigned int packed = 0;
  packed = __builtin_amdgcn_cvt_pk_fp8_f32(o[0], o[1], packed, false); // low word
  packed = __builtin_amdgcn_cvt_pk_fp8_f32(o[2], o[3], packed, true);  // high word
  conc_t[v] = packed;
}

// Kernel 2: per (d, v) ray sums over 110 path entries. 16 lanes cooperate
// (15 lanes x 7 entries + 1 lane x 5). Empirical law from R4/R5: throughput
// scales with resident waves (many shallow waves keep the divergent-gather
// TA pipe fed), so this splits the ray 2x finer than R4 and doubles the grid.
// After 4 xor-shuffle rounds, lanes 0..7 of the group emit the 8 lines:
// expval[d][l][v] = exp(-sum_e FL[e,l]*per_ray[e]).
__global__ __launch_bounds__(256) void k_rays(
    const int* __restrict__ P_idx, const float* __restrict__ P_len,
    const unsigned int* __restrict__ conc_t, const float* __restrict__ FLp,
    float* __restrict__ expval)
{
  int q = threadIdx.x & 15;                         // 1/16 of the ray
  int ray = (blockIdx.x << 4) | (threadIdx.x >> 4); // (d,v) id, 0..65535
  int d = ray >> 9;
  int v = ray & 511;
  size_t off = (size_t)d * NK + (size_t)v * NDIA + (size_t)(q * 7);
  const int*   ip = P_idx + off;
  const float* lp = P_len + off;
  int cnt = (q == 15) ? 5 : 7;                      // 15*7 + 5 = 110
  float a0 = 0.f, a1 = 0.f, a2 = 0.f, a3 = 0.f;
#pragma unroll
  for (int t = 0; t < 7; t++) {
    if (t < cnt) {
      int   idx = ip[t];
      float ln  = lp[t];
      unsigned int u = conc_t[idx];
      v2f c01 = __builtin_amdgcn_cvt_pk_f32_fp8(u, false);
      v2f c23 = __builtin_amdgcn_cvt_pk_f32_fp8(u, true);
      a0 += c01.x * ln;
      a1 += c01.y * ln;
      a2 += c23.x * ln;
      a3 += c23.y * ln;
    }
  }
  // combine the 16 cooperating lanes (adjacent in the wave)
  a0 += __shfl_xor(a0, 1); a1 += __shfl_xor(a1, 1);
  a2 += __shfl_xor(a2, 1); a3 += __shfl_xor(a3, 1);
  a0 += __shfl_xor(a0, 2); a1 += __shfl_xor(a1, 2);
  a2 += __shfl_xor(a2, 2); a3 += __shfl_xor(a3, 2);
  a0 += __shfl_xor(a0, 4); a1 += __shfl_xor(a1, 4);
  a2 += __shfl_xor(a2, 4); a3 += __shfl_xor(a3, 4);
  a0 += __shfl_xor(a0, 8); a1 += __shfl_xor(a1, 8);
  a2 += __shfl_xor(a2, 8); a3 += __shfl_xor(a3, 8);
  if (q < 8) {                                      // lane q emits line l=q
    float s = FLp[q] * a0 + FLp[8 + q] * a1 + FLp[16 + q] * a2 + FLp[24 + q] * a3;
    expval[((size_t)d << 12) + ((size_t)q << 9) + v] = __expf(-s);
  }
}

// Kernel 3: SA = mean_d expval; apply probe attenuation (shfl prefix scan) and
// fl_map, reduce over n. Block = (l,b); 256 threads = 4 d-chunks x 64 n.
__global__ __launch_bounds__(256) void k_final(
    const float* __restrict__ expval, const float* __restrict__ xp,
    const float* __restrict__ attCS, const float* __restrict__ dfl,
    const float* __restrict__ scm, const float* __restrict__ pcts,
    const int* __restrict__ l2e, float* __restrict__ out)
{
  __shared__ float red[256];
  int l = blockIdx.x >> 3;
  int b = blockIdx.x & 7;
  int n = threadIdx.x & 63;
  int dc = threadIdx.x >> 6;                        // d-chunk 0..3
  int v = (b << 6) | n;
  const float* ep = expval + (l << 9) + v;
  float s = 0.f;
#pragma unroll
  for (int t = 0; t < 32; t++) s += ep[(size_t)(dc * 32 + t) << 12];
  red[threadIdx.x] = s;
  __syncthreads();
  if (dc == 0) {
    float sa = red[n] + red[n + 64] + red[n + 128] + red[n + 192];
    float dx = scm[0] * (1.0f / 64.0f);
    float pc = pcts[0];
    float lac = attCS[0] * xp[v] + attCS[1] * xp[512 + v]
              + attCS[2] * xp[1024 + v] + attCS[3] * xp[1536 + v];
    // inclusive prefix scan of lac over the 64 lanes (n)
    float inc = lac;
#pragma unroll
    for (int ofs = 1; ofs < 64; ofs <<= 1) {
      float t = __shfl_up(inc, ofs, 64);
      if (n >= ofs) inc += t;
    }
    float pre = inc - lac;                          // exclusive prefix
    float att = __expf(-dx * pre);
    float val = pc * att * xp[(l2e[l] << 9) + v] * dfl[l] * sa * (1.0f / 128.0f);
#pragma unroll
    for (int ofs = 32; ofs > 0; ofs >>= 1) val += __shfl_down(val, ofs, 64);
    if (n == 0) out[(l << 3) + b] = val;
    if (l == 0 && n == 63) out[64 + b] = pc * __expf(-dx * inc);
  }
}

extern "C" void kernel_launch(void* const* d_in, const int* in_sizes, int n_in,
                              void* d_out, int out_size, void* d_ws, size_t ws_size,
                              hipStream_t stream) {
  const float* grid_c   = (const float*)d_in[0];   // (E,H,N,N)
  const float* xp       = (const float*)d_in[1];   // (E,B,N)
  const float* theta_ls = (const float*)d_in[2];   // (16,)
  const float* attCS    = (const float*)d_in[3];   // (E,)
  const float* FLp      = (const float*)d_in[4];   // (E,L)
  const float* dfl      = (const float*)d_in[5];   // (L,)
  const float* P_len    = (const float*)d_in[6];   // (D,K)
  const float* scm      = (const float*)d_in[7];   // scalar
  const float* pcts     = (const float*)d_in[8];   // scalar
  const int*   l2e      = (const int*)d_in[9];     // (L,)
  const int*   P_idx    = (const int*)d_in[10];    // (D,K)
  const int*   tidx     = (const int*)d_in[11];    // scalar
  const int*   pscal    = (const int*)d_in[12];    // scalar
  float* out = (float*)d_out;                      // 64 (out1) + 8 (out2)

  unsigned int* conc_t = (unsigned int*)d_ws;      // NVOX * 4 B = 1 MB
  float* expval = (float*)((char*)d_ws + (size_t)NVOX * 4); // D*L*BN floats = 2 MB

  k_rotate<<<NVOX / 256, 256, 0, stream>>>(grid_c, xp, theta_ls, tidx, pscal, conc_t);
  k_rays<<<(ND * NBN) / 16, 256, 0, stream>>>(P_idx, P_len, conc_t, FLp, expval);
  k_final<<<NL * NB, 256, 0, stream>>>(expval, xp, attCS, dfl, scm, pcts, l2e, out);
}

// Round 7
// 148.248 us; speedup vs baseline: 1.0340x; 1.0125x over previous
//
#include <hip/hip_runtime.h>
#include <math.h>

// Problem constants (fixed by the reference)
#define NE   4
#define NH   64
#define NG   64            // N
#define NB   8
#define NL   8
#define ND   128
#define NDIA 110
#define NK   (NDIA*NB*NG)  // 56320
#define NBN  (NB*NG)       // 512
#define NVOX (NH*NG*NG)    // 262144

typedef int   v2i __attribute__((ext_vector_type(2)));
typedef float v2f __attribute__((ext_vector_type(2)));

// Kernel 1: rotate grid_concentration (bilinear, zero-pad) + xp overwrite,
// store voxel-major OCP fp8(e4m3)x4: conc_t[v] = pack{conc[e=0..3, v]}.
// 4 B/voxel -> 1 MB table, fully L2-resident (verified R4: FETCH at
// stream-only level).
__global__ __launch_bounds__(256) void k_rotate(
    const float* __restrict__ grid, const float* __restrict__ xp,
    const float* __restrict__ theta_ls, const int* __restrict__ tidx,
    const int* __restrict__ pscal, unsigned int* __restrict__ conc_t)
{
  int v = blockIdx.x * 256 + threadIdx.x;          // voxel id, 0..NVOX-1
  int h = v >> 12;
  int i = (v >> 6) & 63;                            // row
  int j = v & 63;                                   // col
  float theta = theta_ls[tidx[0]];
  float st, ct;
  sincosf(theta, &st, &ct);
  const float c = 31.5f;                            // (N-1)/2
  float x = (float)j - c, y = (float)i - c;
  float xs = ct * x - st * y + c;
  float ys = st * x + ct * y + c;
  float x0f = floorf(xs), y0f = floorf(ys);
  int x0 = (int)x0f, y0 = (int)y0f;
  float wx = xs - x0f, wy = ys - y0f;
  int x1 = x0 + 1, y1 = y0 + 1;
  bool vx0 = (unsigned)x0 < 64u, vx1 = (unsigned)x1 < 64u;
  bool vy0 = (unsigned)y0 < 64u, vy1 = (unsigned)y1 < 64u;
  float w00 = (vy0 && vx0) ? (1.f - wy) * (1.f - wx) : 0.f;
  float w01 = (vy0 && vx1) ? (1.f - wy) * wx         : 0.f;
  float w10 = (vy1 && vx0) ? wy * (1.f - wx)         : 0.f;
  float w11 = (vy1 && vx1) ? wy * wx                 : 0.f;
  int xc0 = min(max(x0, 0), 63), xc1 = min(max(x1, 0), 63);
  int yc0 = min(max(y0, 0), 63), yc1 = min(max(y1, 0), 63);
  int i00 = yc0 * 64 + xc0, i01 = yc0 * 64 + xc1;
  int i10 = yc1 * 64 + xc0, i11 = yc1 * 64 + xc1;
  int hn = (h << 6) | i;                            // flattened H*N row
  int pb = 8 * pscal[0];                            // B*p
  bool ov = (hn >= pb) && (hn < pb + 8);
  int xoff = ov ? (((hn - pb) << 6) | j) : 0;
  float o[4];
#pragma unroll
  for (int e = 0; e < NE; e++) {
    const float* g = grid + (((e << 6) + h) << 12); // (e*H + h)*N*N
    float val = w00 * g[i00] + w01 * g[i01] + w10 * g[i10] + w11 * g[i11];
    if (ov) val = xp[(e << 9) + xoff];              // xp[e, hn-pb, j]
    o[e] = val;
  }
  unsigned int packed = 0;
  packed = __builtin_amdgcn_cvt_pk_fp8_f32(o[0], o[1], packed, false); // low word
  packed = __builtin_amdgcn_cvt_pk_fp8_f32(o[2], o[3], packed, true);  // high word
  conc_t[v] = packed;
}

// Kernel 2: per (d, v) ray sums over 110 path entries (8 lanes cooperate,
// 14x7 + 12 split -- the best shape from R4/R5/R6). Conc-table gathers use
// agent-scope loads (sc0 -> vL1 bypass): every gather misses the 32KB L1
// against the 1MB table anyway, and skipping L1 allocation removes the
// per-miss line-fill serialization. Each lane then emits one line l=q:
// expval[d][l][v] = exp(-sum_e FL[e,l]*per_ray[e]).
__global__ __launch_bounds__(256) void k_rays(
    const int* __restrict__ P_idx, const float* __restrict__ P_len,
    const unsigned int* __restrict__ conc_t, const float* __restrict__ FLp,
    float* __restrict__ expval)
{
  int q = threadIdx.x & 7;                          // eighth of the ray / line id
  int ray = (blockIdx.x << 5) | (threadIdx.x >> 3); // (d,v) id, 0..65535
  int d = ray >> 9;
  int v = ray & 511;
  // per-lane FL coefficients for line l = q
  float fl0 = FLp[q], fl1 = FLp[8 + q], fl2 = FLp[16 + q], fl3 = FLp[24 + q];
  size_t off = (size_t)d * NK + (size_t)v * NDIA + (size_t)(q * 14);
  const v2i* ip = (const v2i*)(P_idx + off);
  const v2f* lp = (const v2f*)(P_len + off);
  int cnt = (q == 7) ? 6 : 7;                       // int2 pairs (tail lane: 12 entries)
  float a0 = 0.f, a1 = 0.f, a2 = 0.f, a3 = 0.f;
#pragma unroll
  for (int t = 0; t < 7; t++) {
    if (t < cnt) {
      v2i id = ip[t];
      v2f ln = lp[t];
      unsigned int u0 = __hip_atomic_load(conc_t + id.x, __ATOMIC_RELAXED,
                                          __HIP_MEMORY_SCOPE_AGENT);
      unsigned int u1 = __hip_atomic_load(conc_t + id.y, __ATOMIC_RELAXED,
                                          __HIP_MEMORY_SCOPE_AGENT);
      v2f c01 = __builtin_amdgcn_cvt_pk_f32_fp8(u0, false);
      v2f c23 = __builtin_amdgcn_cvt_pk_f32_fp8(u0, true);
      v2f d01 = __builtin_amdgcn_cvt_pk_f32_fp8(u1, false);
      v2f d23 = __builtin_amdgcn_cvt_pk_f32_fp8(u1, true);
      a0 += c01.x * ln.x + d01.x * ln.y;
      a1 += c01.y * ln.x + d01.y * ln.y;
      a2 += c23.x * ln.x + d23.x * ln.y;
      a3 += c23.y * ln.x + d23.y * ln.y;
    }
  }
  // combine the 8 cooperating lanes (adjacent in the wave)
  a0 += __shfl_xor(a0, 1); a1 += __shfl_xor(a1, 1);
  a2 += __shfl_xor(a2, 1); a3 += __shfl_xor(a3, 1);
  a0 += __shfl_xor(a0, 2); a1 += __shfl_xor(a1, 2);
  a2 += __shfl_xor(a2, 2); a3 += __shfl_xor(a3, 2);
  a0 += __shfl_xor(a0, 4); a1 += __shfl_xor(a1, 4);
  a2 += __shfl_xor(a2, 4); a3 += __shfl_xor(a3, 4);
  float s = fl0 * a0 + fl1 * a1 + fl2 * a2 + fl3 * a3;
  expval[((size_t)d << 12) + ((size_t)q << 9) + v] = __expf(-s);
}

// Kernel 3: SA = mean_d expval; apply probe attenuation (shfl prefix scan) and
// fl_map, reduce over n. Block = (l,b); 256 threads = 4 d-chunks x 64 n.
__global__ __launch_bounds__(256) void k_final(
    const float* __restrict__ expval, const float* __restrict__ xp,
    const float* __restrict__ attCS, const float* __restrict__ dfl,
    const float* __restrict__ scm, const float* __restrict__ pcts,
    const int* __restrict__ l2e, float* __restrict__ out)
{
  __shared__ float red[256];
  int l = blockIdx.x >> 3;
  int b = blockIdx.x & 7;
  int n = threadIdx.x & 63;
  int dc = threadIdx.x >> 6;                        // d-chunk 0..3
  int v = (b << 6) | n;
  const float* ep = expval + (l << 9) + v;
  float s = 0.f;
#pragma unroll
  for (int t = 0; t < 32; t++) s += ep[(size_t)(dc * 32 + t) << 12];
  red[threadIdx.x] = s;
  __syncthreads();
  if (dc == 0) {
    float sa = red[n] + red[n + 64] + red[n + 128] + red[n + 192];
    float dx = scm[0] * (1.0f / 64.0f);
    float pc = pcts[0];
    float lac = attCS[0] * xp[v] + attCS[1] * xp[512 + v]
              + attCS[2] * xp[1024 + v] + attCS[3] * xp[1536 + v];
    // inclusive prefix scan of lac over the 64 lanes (n)
    float inc = lac;
#pragma unroll
    for (int ofs = 1; ofs < 64; ofs <<= 1) {
      float t = __shfl_up(inc, ofs, 64);
      if (n >= ofs) inc += t;
    }
    float pre = inc - lac;                          // exclusive prefix
    float att = __expf(-dx * pre);
    float val = pc * att * xp[(l2e[l] << 9) + v] * dfl[l] * sa * (1.0f / 128.0f);
#pragma unroll
    for (int ofs = 32; ofs > 0; ofs >>= 1) val += __shfl_down(val, ofs, 64);
    if (n == 0) out[(l << 3) + b] = val;
    if (l == 0 && n == 63) out[64 + b] = pc * __expf(-dx * inc);
  }
}

extern "C" void kernel_launch(void* const* d_in, const int* in_sizes, int n_in,
                              void* d_out, int out_size, void* d_ws, size_t ws_size,
                              hipStream_t stream) {
  const float* grid_c   = (const float*)d_in[0];   // (E,H,N,N)
  const float* xp       = (const float*)d_in[1];   // (E,B,N)
  const float* theta_ls = (const float*)d_in[2];   // (16,)
  const float* attCS    = (const float*)d_in[3];   // (E,)
  const float* FLp      = (const float*)d_in[4];   // (E,L)
  const float* dfl      = (const float*)d_in[5];   // (L,)
  const float* P_len    = (const float*)d_in[6];   // (D,K)
  const float* scm      = (const float*)d_in[7];   // scalar
  const float* pcts     = (const float*)d_in[8];   // scalar
  const int*   l2e      = (const int*)d_in[9];     // (L,)
  const int*   P_idx    = (const int*)d_in[10];    // (D,K)
  const int*   tidx     = (const int*)d_in[11];    // scalar
  const int*   pscal    = (const int*)d_in[12];    // scalar
  float* out = (float*)d_out;                      // 64 (out1) + 8 (out2)

  unsigned int* conc_t = (unsigned int*)d_ws;      // NVOX * 4 B = 1 MB
  float* expval = (float*)((char*)d_ws + (size_t)NVOX * 4); // D*L*BN floats = 2 MB

  k_rotate<<<NVOX / 256, 256, 0, stream>>>(grid_c, xp, theta_ls, tidx, pscal, conc_t);
  k_rays<<<(ND * NBN) / 32, 256, 0, stream>>>(P_idx, P_len, conc_t, FLp, expval);
  k_final<<<NL * NB, 256, 0, stream>>>(expval, xp, attCS, dfl, scm, pcts, l2e, out);
}

// Round 8
// 147.229 us; speedup vs baseline: 1.0411x; 1.0069x over previous
//
#include <hip/hip_runtime.h>
#include <math.h>

// Problem constants (fixed by the reference)
#define NE   4
#define NH   64
#define NG   64            // N
#define NB   8
#define NL   8
#define ND   128
#define NDIA 110
#define NK   (NDIA*NB*NG)  // 56320
#define NBN  (NB*NG)       // 512
#define NVOX (NH*NG*NG)    // 262144

typedef int   v2i __attribute__((ext_vector_type(2)));
typedef float v2f __attribute__((ext_vector_type(2)));

// Kernel 1: rotate grid_concentration (bilinear, zero-pad) + xp overwrite,
// store voxel-major OCP fp8(e4m3)x4: conc_t[v] = pack{conc[e=0..3, v]}.
// 4 B/voxel -> 1 MB table, fully L2-resident (verified R4: FETCH at
// stream-only level).
__global__ __launch_bounds__(256) void k_rotate(
    const float* __restrict__ grid, const float* __restrict__ xp,
    const float* __restrict__ theta_ls, const int* __restrict__ tidx,
    const int* __restrict__ pscal, unsigned int* __restrict__ conc_t)
{
  int v = blockIdx.x * 256 + threadIdx.x;          // voxel id, 0..NVOX-1
  int h = v >> 12;
  int i = (v >> 6) & 63;                            // row
  int j = v & 63;                                   // col
  float theta = theta_ls[tidx[0]];
  float st, ct;
  sincosf(theta, &st, &ct);
  const float c = 31.5f;                            // (N-1)/2
  float x = (float)j - c, y = (float)i - c;
  float xs = ct * x - st * y + c;
  float ys = st * x + ct * y + c;
  float x0f = floorf(xs), y0f = floorf(ys);
  int x0 = (int)x0f, y0 = (int)y0f;
  float wx = xs - x0f, wy = ys - y0f;
  int x1 = x0 + 1, y1 = y0 + 1;
  bool vx0 = (unsigned)x0 < 64u, vx1 = (unsigned)x1 < 64u;
  bool vy0 = (unsigned)y0 < 64u, vy1 = (unsigned)y1 < 64u;
  float w00 = (vy0 && vx0) ? (1.f - wy) * (1.f - wx) : 0.f;
  float w01 = (vy0 && vx1) ? (1.f - wy) * wx         : 0.f;
  float w10 = (vy1 && vx0) ? wy * (1.f - wx)         : 0.f;
  float w11 = (vy1 && vx1) ? wy * wx                 : 0.f;
  int xc0 = min(max(x0, 0), 63), xc1 = min(max(x1, 0), 63);
  int yc0 = min(max(y0, 0), 63), yc1 = min(max(y1, 0), 63);
  int i00 = yc0 * 64 + xc0, i01 = yc0 * 64 + xc1;
  int i10 = yc1 * 64 + xc0, i11 = yc1 * 64 + xc1;
  int hn = (h << 6) | i;                            // flattened H*N row
  int pb = 8 * pscal[0];                            // B*p
  bool ov = (hn >= pb) && (hn < pb + 8);
  int xoff = ov ? (((hn - pb) << 6) | j) : 0;
  float o[4];
#pragma unroll
  for (int e = 0; e < NE; e++) {
    const float* g = grid + (((e << 6) + h) << 12); // (e*H + h)*N*N
    float val = w00 * g[i00] + w01 * g[i01] + w10 * g[i10] + w11 * g[i11];
    if (ov) val = xp[(e << 9) + xoff];              // xp[e, hn-pb, j]
    o[e] = val;
  }
  unsigned int packed = 0;
  packed = __builtin_amdgcn_cvt_pk_fp8_f32(o[0], o[1], packed, false); // low word
  packed = __builtin_amdgcn_cvt_pk_fp8_f32(o[2], o[3], packed, true);  // high word
  conc_t[v] = packed;
}

// Kernel 2: per (d, v) ray sums over 110 path entries (8 lanes cooperate,
// 14x7 + 12 split). Fully branchless, phase-split inner loop:
//   phase 1: clause-load all 7 int2 + 7 float2 stream pairs into registers
//   phase 2: issue all 14 table gathers in one clause (max per-wave MLP)
//   phase 3: fp8 decode + FMA
// Tail lane (q==7) has only 12 entries: its 7th pair is clamped to slot 0
// with zeroed weights (branchless, no OOB).
__global__ __launch_bounds__(256) void k_rays(
    const int* __restrict__ P_idx, const float* __restrict__ P_len,
    const unsigned int* __restrict__ conc_t, const float* __restrict__ FLp,
    float* __restrict__ expval)
{
  int q = threadIdx.x & 7;                          // eighth of the ray / line id
  int ray = (blockIdx.x << 5) | (threadIdx.x >> 3); // (d,v) id, 0..65535
  int d = ray >> 9;
  int v = ray & 511;
  float fl0 = FLp[q], fl1 = FLp[8 + q], fl2 = FLp[16 + q], fl3 = FLp[24 + q];
  size_t off = (size_t)d * NK + (size_t)v * NDIA + (size_t)(q * 14);
  const v2i* ip = (const v2i*)(P_idx + off);
  const v2f* lp = (const v2f*)(P_len + off);
  bool tail = (q == 7);

  // phase 1: stream loads (contiguous, coalesced across the wave)
  v2i idb[7];
  v2f lnb[7];
#pragma unroll
  for (int t = 0; t < 6; t++) { idb[t] = ip[t]; lnb[t] = lp[t]; }
  {
    int t6 = tail ? 0 : 6;                          // clamp OOB pair to slot 0
    idb[6] = ip[t6];
    lnb[6] = lp[t6];
    if (tail) { lnb[6].x = 0.f; lnb[6].y = 0.f; }   // zero duplicated weights
  }

  // phase 2: all 14 gathers in flight
  unsigned int g[14];
#pragma unroll
  for (int t = 0; t < 7; t++) {
    g[2 * t]     = conc_t[idb[t].x];
    g[2 * t + 1] = conc_t[idb[t].y];
  }

  // phase 3: decode + accumulate
  float a0 = 0.f, a1 = 0.f, a2 = 0.f, a3 = 0.f;
#pragma unroll
  for (int t = 0; t < 7; t++) {
    v2f c01 = __builtin_amdgcn_cvt_pk_f32_fp8(g[2 * t], false);
    v2f c23 = __builtin_amdgcn_cvt_pk_f32_fp8(g[2 * t], true);
    v2f d01 = __builtin_amdgcn_cvt_pk_f32_fp8(g[2 * t + 1], false);
    v2f d23 = __builtin_amdgcn_cvt_pk_f32_fp8(g[2 * t + 1], true);
    a0 += c01.x * lnb[t].x + d01.x * lnb[t].y;
    a1 += c01.y * lnb[t].x + d01.y * lnb[t].y;
    a2 += c23.x * lnb[t].x + d23.x * lnb[t].y;
    a3 += c23.y * lnb[t].x + d23.y * lnb[t].y;
  }

  // combine the 8 cooperating lanes (adjacent in the wave)
  a0 += __shfl_xor(a0, 1); a1 += __shfl_xor(a1, 1);
  a2 += __shfl_xor(a2, 1); a3 += __shfl_xor(a3, 1);
  a0 += __shfl_xor(a0, 2); a1 += __shfl_xor(a1, 2);
  a2 += __shfl_xor(a2, 2); a3 += __shfl_xor(a3, 2);
  a0 += __shfl_xor(a0, 4); a1 += __shfl_xor(a1, 4);
  a2 += __shfl_xor(a2, 4); a3 += __shfl_xor(a3, 4);
  float s = fl0 * a0 + fl1 * a1 + fl2 * a2 + fl3 * a3;
  expval[((size_t)d << 12) + ((size_t)q << 9) + v] = __expf(-s);
}

// Kernel 3: SA = mean_d expval; apply probe attenuation (shfl prefix scan) and
// fl_map, reduce over n. Block = (l,b); 256 threads = 4 d-chunks x 64 n.
__global__ __launch_bounds__(256) void k_final(
    const float* __restrict__ expval, const float* __restrict__ xp,
    const float* __restrict__ attCS, const float* __restrict__ dfl,
    const float* __restrict__ scm, const float* __restrict__ pcts,
    const int* __restrict__ l2e, float* __restrict__ out)
{
  __shared__ float red[256];
  int l = blockIdx.x >> 3;
  int b = blockIdx.x & 7;
  int n = threadIdx.x & 63;
  int dc = threadIdx.x >> 6;                        // d-chunk 0..3
  int v = (b << 6) | n;
  const float* ep = expval + (l << 9) + v;
  float s = 0.f;
#pragma unroll
  for (int t = 0; t < 32; t++) s += ep[(size_t)(dc * 32 + t) << 12];
  red[threadIdx.x] = s;
  __syncthreads();
  if (dc == 0) {
    float sa = red[n] + red[n + 64] + red[n + 128] + red[n + 192];
    float dx = scm[0] * (1.0f / 64.0f);
    float pc = pcts[0];
    float lac = attCS[0] * xp[v] + attCS[1] * xp[512 + v]
              + attCS[2] * xp[1024 + v] + attCS[3] * xp[1536 + v];
    // inclusive prefix scan of lac over the 64 lanes (n)
    float inc = lac;
#pragma unroll
    for (int ofs = 1; ofs < 64; ofs <<= 1) {
      float t = __shfl_up(inc, ofs, 64);
      if (n >= ofs) inc += t;
    }
    float pre = inc - lac;                          // exclusive prefix
    float att = __expf(-dx * pre);
    float val = pc * att * xp[(l2e[l] << 9) + v] * dfl[l] * sa * (1.0f / 128.0f);
#pragma unroll
    for (int ofs = 32; ofs > 0; ofs >>= 1) val += __shfl_down(val, ofs, 64);
    if (n == 0) out[(l << 3) + b] = val;
    if (l == 0 && n == 63) out[64 + b] = pc * __expf(-dx * inc);
  }
}

extern "C" void kernel_launch(void* const* d_in, const int* in_sizes, int n_in,
                              void* d_out, int out_size, void* d_ws, size_t ws_size,
                              hipStream_t stream) {
  const float* grid_c   = (const float*)d_in[0];   // (E,H,N,N)
  const float* xp       = (const float*)d_in[1];   // (E,B,N)
  const float* theta_ls = (const float*)d_in[2];   // (16,)
  const float* attCS    = (const float*)d_in[3];   // (E,)
  const float* FLp      = (const float*)d_in[4];   // (E,L)
  const float* dfl      = (const float*)d_in[5];   // (L,)
  const float* P_len    = (const float*)d_in[6];   // (D,K)
  const float* scm      = (const float*)d_in[7];   // scalar
  const float* pcts     = (const float*)d_in[8];   // scalar
  const int*   l2e      = (const int*)d_in[9];     // (L,)
  const int*   P_idx    = (const int*)d_in[10];    // (D,K)
  const int*   tidx     = (const int*)d_in[11];    // scalar
  const int*   pscal    = (const int*)d_in[12];    // scalar
  float* out = (float*)d_out;                      // 64 (out1) + 8 (out2)

  unsigned int* conc_t = (unsigned int*)d_ws;      // NVOX * 4 B = 1 MB
  float* expval = (float*)((char*)d_ws + (size_t)NVOX * 4); // D*L*BN floats = 2 MB

  k_rotate<<<NVOX / 256, 256, 0, stream>>>(grid_c, xp, theta_ls, tidx, pscal, conc_t);
  k_rays<<<(ND * NBN) / 32, 256, 0, stream>>>(P_idx, P_len, conc_t, FLp, expval);
  k_final<<<NL * NB, 256, 0, stream>>>(expval, xp, attCS, dfl, scm, pcts, l2e, out);
}